// Round 3
// baseline (53.371 us; speedup 1.0000x reference)
//
#include <hip/hip_runtime.h>

// NoiseLearnModule: out = x + where(0<=bin<16, eps * sigmoid(params[f,bin]) * 0.1, 0)
// bin = searchsorted(bins[f], x, side='right') - 1
// x,eps [65536,256] f32; bins [256,17] f32; params [256*16] f32.
//
// R3 structure: 4 features/thread, bin edges in 68 REGISTERS (loop-invariant,
// launch_bounds(256,4) so they actually fit), float4 I/O, sigmoid table in
// padded-stride LDS (data-dependent gather, ~2-4-way conflicts).

#define NFEAT 256
#define NBINS 16
#define NEDGE 17
#define SPAD  257                 // scale-row stride (pad breaks 8-way conflicts)
#define NOISE_SCALE 0.1f

__global__ __launch_bounds__(256, 4) void noise_learn_kernel(
    const float* __restrict__ x,
    const float* __restrict__ bins,
    const float* __restrict__ eps,
    const float* __restrict__ params,
    float* __restrict__ out,
    int total4)
{
    // 4352 floats = 17408 B. Reused: bins staging, then scale table [16][257]
    // (4112 floats <= 4352).
    __shared__ float s_mem[NEDGE * NFEAT];

    const int t = threadIdx.x;

    // --- Stage bins coalesced into LDS (natural layout) ---
    #pragma unroll
    for (int i = t; i < NEDGE * NFEAT; i += 256)   // 17 exact iters
        s_mem[i] = bins[i];
    __syncthreads();

    // --- Hoist this thread's 4 features' edges into registers (one-time) ---
    const int f0 = (t & 63) * 4;                   // grid stride is mult of 64
    float e[4][NEDGE];
    #pragma unroll
    for (int j = 0; j < 4; ++j)
        #pragma unroll
        for (int i = 0; i < NEDGE; ++i)
            e[j][i] = s_mem[(f0 + j) * NEDGE + i];
    __syncthreads();

    // --- Overwrite LDS with sigmoid table, layout [k][SPAD] ---
    // Coalesced global read params[i], scatter-write transposed.
    #pragma unroll
    for (int i = t; i < NFEAT * NBINS; i += 256) { // 16 exact iters
        const float p = params[i];
        const int f = i >> 4;                      // i / NBINS
        const int k = i & (NBINS - 1);             // i % NBINS
        s_mem[k * SPAD + f] = 1.0f / (1.0f + __expf(-p));
    }
    __syncthreads();

    const int gid = blockIdx.x * 256 + t;
    const int stride = gridDim.x * 256;

    for (int g = gid; g < total4; g += stride) {
        const float4 xv = reinterpret_cast<const float4*>(x)[g];
        const float4 ev = reinterpret_cast<const float4*>(eps)[g];

        int c0 = 0, c1 = 0, c2 = 0, c3 = 0;        // #edges <= x (side='right')
        #pragma unroll
        for (int i = 0; i < NEDGE; ++i) {
            c0 += (e[0][i] <= xv.x) ? 1 : 0;
            c1 += (e[1][i] <= xv.y) ? 1 : 0;
            c2 += (e[2][i] <= xv.z) ? 1 : 0;
            c3 += (e[3][i] <= xv.w) ? 1 : 0;
        }

        float4 ov;
        {
            const int idx = c0 - 1;
            const int jc = idx < 0 ? 0 : (idx > NBINS - 1 ? NBINS - 1 : idx);
            const float sc = s_mem[jc * SPAD + f0 + 0];
            ov.x = xv.x + (((unsigned)idx < (unsigned)NBINS) ? ev.x * sc * NOISE_SCALE : 0.0f);
        }
        {
            const int idx = c1 - 1;
            const int jc = idx < 0 ? 0 : (idx > NBINS - 1 ? NBINS - 1 : idx);
            const float sc = s_mem[jc * SPAD + f0 + 1];
            ov.y = xv.y + (((unsigned)idx < (unsigned)NBINS) ? ev.y * sc * NOISE_SCALE : 0.0f);
        }
        {
            const int idx = c2 - 1;
            const int jc = idx < 0 ? 0 : (idx > NBINS - 1 ? NBINS - 1 : idx);
            const float sc = s_mem[jc * SPAD + f0 + 2];
            ov.z = xv.z + (((unsigned)idx < (unsigned)NBINS) ? ev.z * sc * NOISE_SCALE : 0.0f);
        }
        {
            const int idx = c3 - 1;
            const int jc = idx < 0 ? 0 : (idx > NBINS - 1 ? NBINS - 1 : idx);
            const float sc = s_mem[jc * SPAD + f0 + 3];
            ov.w = xv.w + (((unsigned)idx < (unsigned)NBINS) ? ev.w * sc * NOISE_SCALE : 0.0f);
        }

        reinterpret_cast<float4*>(out)[g] = ov;
    }
}

extern "C" void kernel_launch(void* const* d_in, const int* in_sizes, int n_in,
                              void* d_out, int out_size, void* d_ws, size_t ws_size,
                              hipStream_t stream) {
    const float* x      = (const float*)d_in[0];
    const float* bins   = (const float*)d_in[1];
    const float* eps    = (const float*)d_in[2];
    const float* params = (const float*)d_in[3];
    float* out = (float*)d_out;

    const int total4 = out_size / 4;   // 4,194,304 float4 groups
    dim3 block(256);
    dim3 grid(2048);                   // 8 iters/thread; 8 blocks/CU scheduled
    noise_learn_kernel<<<grid, block, 0, stream>>>(x, bins, eps, params, out, total4);
}